// Round 6
// baseline (331.245 us; speedup 1.0000x reference)
//
#include <hip/hip_runtime.h>

// ---------------- problem constants ----------------
#define DIM     384
#define QKV_CH  1152
#define HD      32
#define CD      128
#define BATCH   4
#define SEQ     8192
#define ROWS    (BATCH*SEQ)   // 32768
#define SCALE   0.17677669529663687f
#define FRAG_STRIDE 6144      // 48*128 shorts per 16-row block (K=384 swizzled)
#define XRB_MAX (ROWS/16 - 1) // 2047

typedef short bf16x8 __attribute__((ext_vector_type(8)));
typedef float f32x4  __attribute__((ext_vector_type(4)));

__device__ __forceinline__ unsigned short f2bf(float f) {
  unsigned int u = __float_as_uint(f);
  u += 0x7fffu + ((u >> 16) & 1u);      // RNE
  return (unsigned short)(u >> 16);
}
__device__ __forceinline__ float bf2f(unsigned short b) {
  return __uint_as_float(((unsigned int)b) << 16);
}
__device__ __forceinline__ float bflo(unsigned int u) { return bf2f((unsigned short)(u & 0xffffu)); }
__device__ __forceinline__ float bfhi(unsigned int u) { return bf2f((unsigned short)(u >> 16)); }
__device__ __forceinline__ unsigned int pack2(float a, float b) {
  return (unsigned int)f2bf(a) | ((unsigned int)f2bf(b) << 16);
}
__device__ __forceinline__ void unpack8(uint4 u, float* f) {
  f[0] = bflo(u.x); f[1] = bfhi(u.x); f[2] = bflo(u.y); f[3] = bfhi(u.y);
  f[4] = bflo(u.z); f[5] = bfhi(u.z); f[6] = bflo(u.w); f[7] = bfhi(u.w);
}

// ================= swizzled (fragment-major) layout =================
// swz(r,k; K=384) = ((r/16)*48 + k/8)*128 + (r%16)*8 + (k%8)

// ---------------- fp32 -> swizzled bf16 convert ----------------
template<int K>
__global__ __launch_bounds__(256) void cvt_swz(const float* __restrict__ in,
                                               unsigned short* __restrict__ out) {
  const int KB = K / 8;
  int cid = blockIdx.x * 256 + threadIdx.x;
  int rl = cid & 15;
  int q  = cid >> 4;
  int rb = q / KB;
  int kb = q - rb * KB;
  const float* p = in + (size_t)(rb * 16 + rl) * K + kb * 8;
  float4 a = *(const float4*)p;
  float4 b = *(const float4*)(p + 4);
  uint4 u;
  u.x = pack2(a.x, a.y); u.y = pack2(a.z, a.w);
  u.z = pack2(b.x, b.y); u.w = pack2(b.z, b.w);
  *(uint4*)(out + (size_t)cid * 8) = u;
}

// ---------------- mega kernel: QKV proj + dilated attn + output proj ----------------
// 512 blocks x 256 threads; block = 64-row tile; d-loop inside; proj running sum
// kept as packed bf16 (48 VGPRs) across the d loop. LDS tiles in MFMA-fragment
// layout (16B chunk = 16 rows x 8 ch): all LDS traffic is contiguous per wave.
__global__ __launch_bounds__(256, 2) void mega_kernel(
    const unsigned short* __restrict__ X,    // x_swz    [ROWS,384] swizzled
    const unsigned short* __restrict__ Wq,   // wqkv_swz [1152,384] swizzled
    const float* __restrict__ bqkv,          // [1152]
    const unsigned short* __restrict__ Wp,   // wproj_swz [384,384] swizzled
    const float* __restrict__ bproj,         // [384]
    float* __restrict__ out) {               // [ROWS,384] fp32 row-major
  __shared__ unsigned short q_t[8192];       // 16 KB: q tile, then attn chunk
  __shared__ unsigned short k_t[12288];      // 24 KB: rows row0-16 .. row0+80
  __shared__ unsigned short v_t[12288];      // 24 KB

  const int t = threadIdx.x;
  const int w = t >> 6, lane = t & 63;
  const int quad = lane >> 4, l16 = lane & 15;
  const int row0 = blockIdx.x * 64;
  const int rb0 = row0 >> 4;

  // x fragment pointers for halo row-blocks rb0-1 .. rb0+4 (clamped at ends;
  // clamped rows only feed taps that are invalid and never read)
  const unsigned short* pa[6];
#pragma unroll
  for (int j = 0; j < 6; ++j) {
    int xrb = rb0 - 1 + j;
    xrb = xrb < 0 ? 0 : (xrb > XRB_MAX ? XRB_MAX : xrb);
    pa[j] = X + (size_t)xrb * FRAG_STRIDE + lane * 8;
  }

  // proj running sum, packed bf16: [j=4 row-blocks][i=6 col-blocks][2]
  unsigned int run[4][6][2];
#pragma unroll
  for (int j = 0; j < 4; ++j)
#pragma unroll
    for (int i = 0; i < 6; ++i) { run[j][i][0] = 0u; run[j][i][1] = 0u; }

  // LDS chunk-index helper: ch_blk = (channel within group)/8 in [0,16)
  // addr(row_l, ch) = ((row_l>>4)*16 + (ch>>3))*128 + (row_l&15)*8 + (ch&7)

#pragma unroll 1
  for (int d = 0; d < 3; ++d) {
    // -------- phase 1a: q + k MFMA (shared x fragments) --------
    {
      const unsigned short *pbq[2], *pbk[2];
#pragma unroll
      for (int c = 0; c < 2; ++c) {
        int wrb = d * 8 + w * 2 + c;
        pbq[c] = Wq + (size_t)wrb * FRAG_STRIDE + lane * 8;
        pbk[c] = Wq + (size_t)(wrb + 24) * FRAG_STRIDE + lane * 8;
      }
      f32x4 aq[4][2] = {}, ak[6][2] = {};
#pragma unroll
      for (int kk = 0; kk < 12; ++kk) {
        bf16x8 a[6];
#pragma unroll
        for (int j = 0; j < 6; ++j) a[j] = *(const bf16x8*)(pa[j] + kk * 512);
        bf16x8 bq[2], bk[2];
#pragma unroll
        for (int c = 0; c < 2; ++c) {
          bq[c] = *(const bf16x8*)(pbq[c] + kk * 512);
          bk[c] = *(const bf16x8*)(pbk[c] + kk * 512);
        }
#pragma unroll
        for (int c = 0; c < 2; ++c) {
#pragma unroll
          for (int j = 0; j < 4; ++j)
            aq[j][c] = __builtin_amdgcn_mfma_f32_16x16x32_bf16(bq[c], a[j + 1], aq[j][c], 0, 0, 0);
#pragma unroll
          for (int j = 0; j < 6; ++j)
            ak[j][c] = __builtin_amdgcn_mfma_f32_16x16x32_bf16(bk[c], a[j], ak[j][c], 0, 0, 0);
        }
      }
      // epilogue -> LDS frag layout. lane holds row l16(+16j), cols colb..colb+3
#pragma unroll
      for (int c = 0; c < 2; ++c) {
        int colb = w * 32 + c * 16 + quad * 4;                  // within 128-ch group
        int cblk = (colb >> 3);                                  // 16B chunk index
        int sub  = (colb & 7);                                   // 0 or 4
        float4 b_q = *(const float4*)&bqkv[d * CD + colb];
        float4 b_k = *(const float4*)&bqkv[384 + d * CD + colb];
#pragma unroll
        for (int j = 0; j < 4; ++j) {
          uint2 u;
          u.x = pack2(aq[j][c][0] + b_q.x, aq[j][c][1] + b_q.y);
          u.y = pack2(aq[j][c][2] + b_q.z, aq[j][c][3] + b_q.w);
          *(uint2*)&q_t[(j * 16 + cblk) * 128 + l16 * 8 + sub] = u;
        }
#pragma unroll
        for (int j = 0; j < 6; ++j) {
          uint2 u;
          u.x = pack2(ak[j][c][0] + b_k.x, ak[j][c][1] + b_k.y);
          u.y = pack2(ak[j][c][2] + b_k.z, ak[j][c][3] + b_k.w);
          *(uint2*)&k_t[(j * 16 + cblk) * 128 + l16 * 8 + sub] = u;
        }
      }
    }
    // -------- phase 1b: v MFMA --------
    {
      const unsigned short* pbv[2];
#pragma unroll
      for (int c = 0; c < 2; ++c)
        pbv[c] = Wq + (size_t)(d * 8 + w * 2 + c + 48) * FRAG_STRIDE + lane * 8;
      f32x4 av[6][2] = {};
#pragma unroll
      for (int kk = 0; kk < 12; ++kk) {
        bf16x8 a[6];
#pragma unroll
        for (int j = 0; j < 6; ++j) a[j] = *(const bf16x8*)(pa[j] + kk * 512);
        bf16x8 bv[2];
#pragma unroll
        for (int c = 0; c < 2; ++c) bv[c] = *(const bf16x8*)(pbv[c] + kk * 512);
#pragma unroll
        for (int c = 0; c < 2; ++c)
#pragma unroll
          for (int j = 0; j < 6; ++j)
            av[j][c] = __builtin_amdgcn_mfma_f32_16x16x32_bf16(bv[c], a[j], av[j][c], 0, 0, 0);
      }
#pragma unroll
      for (int c = 0; c < 2; ++c) {
        int colb = w * 32 + c * 16 + quad * 4;
        int cblk = (colb >> 3), sub = (colb & 7);
        float4 b_v = *(const float4*)&bqkv[768 + d * CD + colb];
#pragma unroll
        for (int j = 0; j < 6; ++j) {
          uint2 u;
          u.x = pack2(av[j][c][0] + b_v.x, av[j][c][1] + b_v.y);
          u.y = pack2(av[j][c][2] + b_v.z, av[j][c][3] + b_v.w);
          *(uint2*)&v_t[(j * 16 + cblk) * 128 + l16 * 8 + sub] = u;
        }
      }
    }
    __syncthreads();

    // -------- phase 2: attention (head h = wave, row r = lane) --------
    {
      const int h = w;
      const int r = lane;
      const int dil = d + 1;
      const int n = (row0 + r) & (SEQ - 1);

      float q[32];
#pragma unroll
      for (int c8 = 0; c8 < 4; ++c8) {
        uint4 u = *(const uint4*)&q_t[((r >> 4) * 16 + h * 4 + c8) * 128 + (r & 15) * 8];
        unpack8(u, &q[c8 * 8]);
      }
      __syncthreads();   // q reads done before chunk overwrites q_t

      float ex[3];
      int   valid[3];
#pragma unroll
      for (int kh = 0; kh < 3; ++kh) {
        int off = (kh - 1) * dil;
        int nn = n + off;
        int v = (nn >= 0) && (nn < SEQ);
        valid[kh] = v;
        float l = 0.f;
        if (v) {
          int rl = r + 16 + off;
#pragma unroll
          for (int c8 = 0; c8 < 4; ++c8) {
            uint4 u = *(const uint4*)&k_t[((rl >> 4) * 16 + h * 4 + c8) * 128 + (rl & 15) * 8];
            float kkv[8]; unpack8(u, kkv);
#pragma unroll
            for (int j = 0; j < 8; ++j) l += q[c8 * 8 + j] * kkv[j];
          }
        }
        ex[kh] = v ? __expf(l * SCALE) : 1.f;   // zero-padded tap -> exp(0)=1
      }
      float inv = 1.f / (ex[0] + ex[1] + ex[2] + 6.f);  // +6 structural zero taps

      float o[32];
#pragma unroll
      for (int e = 0; e < 32; ++e) o[e] = 0.f;
#pragma unroll
      for (int kh = 0; kh < 3; ++kh) {
        if (!valid[kh]) continue;
        int off = (kh - 1) * dil;
        int rl = r + 16 + off;
        float wgt = ex[kh];
#pragma unroll
        for (int c8 = 0; c8 < 4; ++c8) {
          uint4 u = *(const uint4*)&v_t[((rl >> 4) * 16 + h * 4 + c8) * 128 + (rl & 15) * 8];
          float vv[8]; unpack8(u, vv);
#pragma unroll
          for (int j = 0; j < 8; ++j) o[c8 * 8 + j] += wgt * vv[j];
        }
      }
      // write attn chunk into q_t region (frag layout)
#pragma unroll
      for (int c8 = 0; c8 < 4; ++c8) {
        uint4 u;
        u.x = pack2(o[c8*8+0] * inv, o[c8*8+1] * inv);
        u.y = pack2(o[c8*8+2] * inv, o[c8*8+3] * inv);
        u.z = pack2(o[c8*8+4] * inv, o[c8*8+5] * inv);
        u.w = pack2(o[c8*8+6] * inv, o[c8*8+7] * inv);
        *(uint4*)&q_t[((r >> 4) * 16 + h * 4 + c8) * 128 + (r & 15) * 8] = u;
      }
    }
    __syncthreads();

    // -------- phase 3: proj partial for this d (K-chunk = 128 ch) --------
    {
      f32x4 p[4][6] = {};
#pragma unroll
      for (int kk = 0; kk < 4; ++kk) {
        bf16x8 af[4];
#pragma unroll
        for (int j = 0; j < 4; ++j)
          af[j] = *(const bf16x8*)&q_t[j * 2048 + kk * 512 + lane * 8];
#pragma unroll
        for (int i = 0; i < 6; ++i) {
          bf16x8 bf = *(const bf16x8*)(Wp + (size_t)(w * 6 + i) * FRAG_STRIDE
                                          + (d * 16 + kk * 4) * 128 + lane * 8);
#pragma unroll
          for (int j = 0; j < 4; ++j)
            p[j][i] = __builtin_amdgcn_mfma_f32_16x16x32_bf16(bf, af[j], p[j][i], 0, 0, 0);
        }
      }
      // fold into packed bf16 running sum
#pragma unroll
      for (int j = 0; j < 4; ++j)
#pragma unroll
        for (int i = 0; i < 6; ++i) {
          float s0 = bflo(run[j][i][0]) + p[j][i][0];
          float s1 = bfhi(run[j][i][0]) + p[j][i][1];
          float s2 = bflo(run[j][i][1]) + p[j][i][2];
          float s3 = bfhi(run[j][i][1]) + p[j][i][3];
          run[j][i][0] = pack2(s0, s1);
          run[j][i][1] = pack2(s2, s3);
        }
    }
    __syncthreads();   // before next d overwrites q_t/k_t/v_t
  }

  // -------- final epilogue: bias + fp32 stores --------
#pragma unroll
  for (int j = 0; j < 4; ++j) {
    size_t gr = (size_t)(row0 + j * 16 + l16);
#pragma unroll
    for (int i = 0; i < 6; ++i) {
      int gc = (w * 6 + i) * 16 + quad * 4;
      float4 b = *(const float4*)&bproj[gc];
      float4 o;
      o.x = bflo(run[j][i][0]) + b.x;
      o.y = bfhi(run[j][i][0]) + b.y;
      o.z = bflo(run[j][i][1]) + b.z;
      o.w = bfhi(run[j][i][1]) + b.w;
      *(float4*)&out[gr * DIM + gc] = o;
    }
  }
}

// ---------------- launch ----------------
extern "C" void kernel_launch(void* const* d_in, const int* in_sizes, int n_in,
                              void* d_out, int out_size, void* d_ws, size_t ws_size,
                              hipStream_t stream) {
  const float* x     = (const float*)d_in[0];
  const float* Wqkv  = (const float*)d_in[1];
  const float* bqkv  = (const float*)d_in[2];
  const float* Wproj = (const float*)d_in[3];
  const float* bproj = (const float*)d_in[4];
  float* out = (float*)d_out;

  char* ws = (char*)d_ws;
  unsigned short* x_swz     = (unsigned short*)(ws);                // 25,165,824 B
  unsigned short* wqkv_swz  = (unsigned short*)(ws + 25165824);     //    884,736 B
  unsigned short* wproj_swz = (unsigned short*)(ws + 26050560);     //    294,912 B

  cvt_swz<DIM><<<ROWS * (DIM / 8) / 256, 256, 0, stream>>>(x, x_swz);
  cvt_swz<DIM><<<QKV_CH * (DIM / 8) / 256, 256, 0, stream>>>(Wqkv, wqkv_swz);
  cvt_swz<DIM><<<DIM * (DIM / 8) / 256, 256, 0, stream>>>(Wproj, wproj_swz);

  mega_kernel<<<ROWS / 64, 256, 0, stream>>>(x_swz, wqkv_swz, bqkv,
                                             wproj_swz, bproj, out);
}